// Round 5
// baseline (317.747 us; speedup 1.0000x reference)
//
#include <hip/hip_runtime.h>

typedef short bf16x8 __attribute__((ext_vector_type(8)));
typedef float f32x4 __attribute__((ext_vector_type(4)));
typedef unsigned short ushort8 __attribute__((ext_vector_type(8)));
typedef unsigned short ushort4v __attribute__((ext_vector_type(4)));

#define BATCH 16
#define DCAT 512
#define CIN 256
#define COUT 256
#define HH 64
#define WW 64
#define HP 66
#define WP 66
#define PLANE (HP * WP * 8)  // shorts per c8-plane

__device__ __forceinline__ unsigned short f2bf(float f) {
  unsigned int u = __float_as_uint(f);
  unsigned int r = (u + 0x7fffu + ((u >> 16) & 1u)) >> 16;
  return (unsigned short)r;
}

// ---------------- MLP layer: one wave per output element (b,c).
template <int IN_DIM>
__global__ void __launch_bounds__(256) mlp_layer(const float* __restrict__ in,
                                                 const float* __restrict__ w,
                                                 const float* __restrict__ bias,
                                                 float* __restrict__ out) {
  int wid = threadIdx.x >> 6, lane = threadIdx.x & 63;
  int oidx = blockIdx.x * 4 + wid;  // (b<<8)|c
  int b = oidx >> 8, c = oidx & 255;
  const float* wr = w + (size_t)c * IN_DIM;
  const float* ir = in + (size_t)b * IN_DIM;
  float sum = 0.f;
#pragma unroll
  for (int d0 = 0; d0 < IN_DIM; d0 += 256) {
    f32x4 wv = *(const f32x4*)(wr + d0 + lane * 4);
    f32x4 iv = *(const f32x4*)(ir + d0 + lane * 4);
    sum += wv[0] * iv[0] + wv[1] * iv[1] + wv[2] * iv[2] + wv[3] * iv[3];
  }
#pragma unroll
  for (int off = 32; off; off >>= 1) sum += __shfl_xor(sum, off, 64);
  if (lane == 0) {
    float a = sum + bias[c];
    out[oidx] = a >= 0.f ? a : 0.01f * a;
  }
}

// ---------------- weight transpose: conv_w(O,I,3,3) fp32 -> wt[tap][o][i] bf16
__global__ void prep_w(const float* __restrict__ cw, unsigned short* __restrict__ wt) {
  int idx = blockIdx.x * 256 + threadIdx.x;  // 9*256*64 = 147456 threads
  int t = idx / 16384;
  int r = idx - t * 16384;  // o*64 + i4
  int o = r >> 6, i4 = r & 63;
  ushort4v v;
#pragma unroll
  for (int j = 0; j < 4; j++) v[j] = f2bf(cw[(o * 256 + i4 * 4 + j) * 9 + t]);
  *(ushort4v*)(wt + ((size_t)(t * COUT + o)) * CIN + i4 * 4) = v;
}

// ---------------- fused: MLP layer 3 + padded, scaled, c8-blocked bf16 activation.
__global__ void __launch_bounds__(256) mlp3_prep_x(const float* __restrict__ t1,
                                                   const float* __restrict__ w2,
                                                   const float* __restrict__ b2,
                                                   const float* __restrict__ x,
                                                   unsigned short* __restrict__ xpad) {
  int blk = blockIdx.x;  // ((b*32 + c8)<<2) | q
  int q = blk & 3, c8 = (blk >> 2) & 31, b = blk >> 7;
  int tid = threadIdx.x;
  int wid = tid >> 6, lane = tid & 63;

  int gg = q * 256 + tid;
  int hh = (gg >> 4) + 1;
  int w0 = (gg & 15) * 4 + 1;
  int base = (hh - 1) * WW + (w0 - 1);
  const float* xb = x + ((size_t)(b * CIN + c8 * 8)) * (HH * WW);
  f32x4 v[8];
#pragma unroll
  for (int j = 0; j < 8; j++) v[j] = *(const f32x4*)(xb + j * (HH * WW) + base);

  float tv = t1[b * CIN + tid];
  float pj[8];
#pragma unroll
  for (int j = 0; j < 8; j++) pj[j] = w2[(size_t)(c8 * 8 + j) * CIN + tid] * tv;
#pragma unroll
  for (int off = 32; off; off >>= 1)
#pragma unroll
    for (int j = 0; j < 8; j++) pj[j] += __shfl_xor(pj[j], off, 64);
  __shared__ float red[4][8];
  __shared__ float sv_sh[8];
  if (lane == 0)
#pragma unroll
    for (int j = 0; j < 8; j++) red[wid][j] = pj[j];
  __syncthreads();
  if (tid < 8) {
    float a = red[0][tid] + red[1][tid] + red[2][tid] + red[3][tid] + b2[c8 * 8 + tid];
    sv_sh[tid] = a >= 0.f ? a : 0.01f * a;
  }
  __syncthreads();
  float sv[8];
#pragma unroll
  for (int j = 0; j < 8; j++) sv[j] = sv_sh[j];

  unsigned short* xp = xpad + ((size_t)(b * 32 + c8)) * PLANE;

  if (tid < 65) {
    int i = q * 65 + tid;
    int bh, bw;
    if (i < 66) { bh = 0; bw = i; }
    else if (i < 132) { bh = 65; bw = i - 66; }
    else if (i < 196) { bh = i - 132 + 1; bw = 0; }
    else { bh = i - 196 + 1; bw = 65; }
    ushort8 z = {0, 0, 0, 0, 0, 0, 0, 0};
    *(ushort8*)(xp + (bh * WP + bw) * 8) = z;
  }

  unsigned short* op = xp + (hh * WP + w0) * 8;
#pragma unroll
  for (int t2 = 0; t2 < 4; t2++) {
    ushort8 o;
#pragma unroll
    for (int j = 0; j < 8; j++) o[j] = f2bf(v[j][t2] * sv[j]);
    *(ushort8*)(op + t2 * 8) = o;
  }
}

// ---------------- implicit-GEMM conv: BM=128, BN=128, BK=64, 256 thr (2x2 waves)
// A: LDS double-buffered via global_load_lds, prefetched 1 iter ahead.
// B: register fragments straight from wt (no LDS), prefetched 1 iter ahead.
// One barrier per iter; its vmcnt(0) drain finds prefetch already landed.
__device__ __forceinline__ void gl2lds16(const void* g, void* l) {
  __builtin_amdgcn_global_load_lds((const __attribute__((address_space(1))) void*)g,
                                   (__attribute__((address_space(3))) void*)l, 16, 0, 0);
}

__global__ void __launch_bounds__(256, 2) gemm_conv(const unsigned short* __restrict__ xpad,
                                                    const unsigned short* __restrict__ wt,
                                                    float* __restrict__ out) {
  __shared__ unsigned short As[2][128 * 64];  // 2 x 16 KiB, [px][64ch] XOR-swizzled
  int tid = threadIdx.x;
  int wid = tid >> 6, lane = tid & 63;
  int bid = blockIdx.x;  // 1024 blocks
  // XCD x (bid%8) gets m_t in [64x, 64x+64) = 2 contiguous images, both n_t.
  int swz = bid & 7, rest = bid >> 3;
  int n_t = rest & 1;
  int m_t = swz * 64 + (rest >> 1);
  int m0 = m_t << 7;
  int b = m0 >> 12;
  int h0 = (m0 >> 6) & 63;
  int wm = wid & 1, wn = wid >> 1;  // 2x2 waves, each 64(M) x 64(N)

  f32x4 acc[4][4];
#pragma unroll
  for (int mi = 0; mi < 4; mi++)
#pragma unroll
    for (int ni = 0; ni < 4; ni++) acc[mi][ni] = (f32x4){0.f, 0.f, 0.f, 0.f};

  // ---- A stager: 4 issues of 4 KiB; issue j covers px rows [32j,32j+32)
  // LDS offset = j*4KiB + tid*16 (affine in lane ✓); XOR swizzle on global side.
  int prow = tid >> 3;                    // 0..31
  int gsA = (tid & 7) ^ (prow & 7);       // global chunk for slot tid&7 (j-invariant)
  const unsigned short* aBase =
      xpad + ((size_t)((b * 32 + gsA) * HP + h0)) * (WP * 8) + prow * 8;
  // issue offsets (shorts): j=1:+32px; j=2:+1 image row; j=3:+row+32px
  const int AJ[4] = {0, 32 * 8, WP * 8, WP * 8 + 32 * 8};

  // ---- B lane base: o = n_t*128 + wn*64 + ni*16 + (lane&15), k = kb*32+(lane>>4)*8
  const unsigned short* wtLane =
      wt + ((size_t)(n_t * 128 + wn * 64 + (lane & 15))) * CIN + (lane >> 4) * 8;

  // ---- A reader frag offsets (bytes), XOR-unswizzled
  int rA = wm * 64 + (lane & 15);
  int qa = lane >> 4;
  int offA0 = rA * 128 + ((qa ^ (rA & 7)) * 16);
  int offA1 = rA * 128 + (((qa + 4) ^ (rA & 7)) * 16);

  // ---- prologue: stage A(0) into buf0, load B(0)
#pragma unroll
  for (int j = 0; j < 4; j++)
    gl2lds16(aBase + AJ[j], (char*)As[0] + j * 4096 + tid * 16);
  bf16x8 bv[2][4];
#pragma unroll
  for (int kb = 0; kb < 2; kb++)
#pragma unroll
    for (int ni = 0; ni < 4; ni++)
      bv[kb][ni] = *(const bf16x8*)(wtLane + ni * 16 * CIN + kb * 32);
  __syncthreads();

#pragma unroll 2
  for (int kk = 0; kk < 36; kk++) {
    // uniform next-iter offsets (clamped; redundant re-issue on last iter is harmless)
    int kk1 = kk + 1 < 36 ? kk + 1 : 35;
    int tap1 = kk1 >> 2, kc21 = kk1 & 3;
    int kh1 = (tap1 * 11) >> 5;  // tap/3 for 0..8
    int kw1 = tap1 - kh1 * 3;
    int aoff1 = (kh1 * WP + kw1) * 8 + kc21 * (8 * PLANE);
    int boff1 = tap1 * (COUT * CIN) + kc21 * 64;

    // prefetch A(kk+1) -> buf[(kk+1)&1]
    char* dst = (char*)As[(kk + 1) & 1] + tid * 16;
#pragma unroll
    for (int j = 0; j < 4; j++)
      gl2lds16(aBase + AJ[j] + aoff1, dst + j * 4096);

    // prefetch B(kk+1) -> bvn
    bf16x8 bvn[2][4];
#pragma unroll
    for (int kb = 0; kb < 2; kb++)
#pragma unroll
      for (int ni = 0; ni < 4; ni++)
        bvn[kb][ni] = *(const bf16x8*)(wtLane + ni * 16 * CIN + boff1 + kb * 32);

    // compute on buf[kk&1] with bv
    const char* buf = (const char*)As[kk & 1];
#pragma unroll
    for (int kb = 0; kb < 2; kb++) {
      int oa = kb ? offA1 : offA0;
      bf16x8 av[4];
#pragma unroll
      for (int mi = 0; mi < 4; mi++) av[mi] = *(const bf16x8*)(buf + oa + mi * 2048);
#pragma unroll
      for (int mi = 0; mi < 4; mi++)
#pragma unroll
        for (int ni = 0; ni < 4; ni++)
          acc[mi][ni] = __builtin_amdgcn_mfma_f32_16x16x32_bf16(av[mi], bv[kb][ni],
                                                                acc[mi][ni], 0, 0, 0);
    }
    __syncthreads();
#pragma unroll
    for (int kb = 0; kb < 2; kb++)
#pragma unroll
      for (int ni = 0; ni < 4; ni++) bv[kb][ni] = bvn[kb][ni];
  }

  // ---- epilogue: D row = pixel (quad*4+reg), col = o (lane&15)
  int pixbase = m0 & 4095;
  int quad = lane >> 4;
  int col = lane & 15;
#pragma unroll
  for (int mi = 0; mi < 4; mi++) {
    int pm = pixbase + wm * 64 + mi * 16 + quad * 4;
#pragma unroll
    for (int ni = 0; ni < 4; ni++) {
      int on = n_t * 128 + wn * 64 + ni * 16 + col;
      float* op = out + ((size_t)(b * COUT + on) << 12) + pm;
      *(f32x4*)op = acc[mi][ni];
    }
  }
}

extern "C" void kernel_launch(void* const* d_in, const int* in_sizes, int n_in,
                              void* d_out, int out_size, void* d_ws, size_t ws_size,
                              hipStream_t stream) {
  const float* x = (const float*)d_in[0];
  const float* y = (const float*)d_in[1];
  const float* w0 = (const float*)d_in[2];
  const float* b0 = (const float*)d_in[3];
  const float* w1 = (const float*)d_in[4];
  const float* b1 = (const float*)d_in[5];
  const float* w2 = (const float*)d_in[6];
  const float* b2 = (const float*)d_in[7];
  const float* cw = (const float*)d_in[8];
  float* out = (float*)d_out;

  char* ws = (char*)d_ws;
  float* t0 = (float*)ws;                              // 16 KiB
  float* t1 = (float*)(ws + 16384);                    // 16 KiB
  unsigned short* wt = (unsigned short*)(ws + 32768);  // 1.125 MiB
  unsigned short* xpad = (unsigned short*)(ws + 32768 + 9 * COUT * CIN * 2);

  mlp_layer<DCAT><<<BATCH * CIN / 4, 256, 0, stream>>>(y, w0, b0, t0);
  mlp_layer<CIN><<<BATCH * CIN / 4, 256, 0, stream>>>(t0, w1, b1, t1);
  prep_w<<<9 * COUT * CIN / 4 / 256, 256, 0, stream>>>(cw, wt);
  mlp3_prep_x<<<BATCH * 32 * 4, 256, 0, stream>>>(t1, w2, b2, x, xpad);
  gemm_conv<<<BATCH * HH * WW / 128 * 2, 256, 0, stream>>>(xpad, wt, out);
}

// Round 6
// 208.572 us; speedup vs baseline: 1.5234x; 1.5234x over previous
//
#include <hip/hip_runtime.h>

typedef short bf16x8 __attribute__((ext_vector_type(8)));
typedef float f32x4 __attribute__((ext_vector_type(4)));
typedef unsigned short ushort8 __attribute__((ext_vector_type(8)));
typedef unsigned short ushort4v __attribute__((ext_vector_type(4)));

#define BATCH 16
#define DCAT 512
#define CIN 256
#define COUT 256
#define HH 64
#define WW 64
#define HP 66
#define WP 66
#define PLANE (HP * WP * 8)  // shorts per c8-plane

__device__ __forceinline__ unsigned short f2bf(float f) {
  unsigned int u = __float_as_uint(f);
  unsigned int r = (u + 0x7fffu + ((u >> 16) & 1u)) >> 16;
  return (unsigned short)r;
}

// ---------------- MLP layer: one wave per output element (b,c).
template <int IN_DIM>
__global__ void __launch_bounds__(256) mlp_layer(const float* __restrict__ in,
                                                 const float* __restrict__ w,
                                                 const float* __restrict__ bias,
                                                 float* __restrict__ out) {
  int wid = threadIdx.x >> 6, lane = threadIdx.x & 63;
  int oidx = blockIdx.x * 4 + wid;  // (b<<8)|c
  int b = oidx >> 8, c = oidx & 255;
  const float* wr = w + (size_t)c * IN_DIM;
  const float* ir = in + (size_t)b * IN_DIM;
  float sum = 0.f;
#pragma unroll
  for (int d0 = 0; d0 < IN_DIM; d0 += 256) {
    f32x4 wv = *(const f32x4*)(wr + d0 + lane * 4);
    f32x4 iv = *(const f32x4*)(ir + d0 + lane * 4);
    sum += wv[0] * iv[0] + wv[1] * iv[1] + wv[2] * iv[2] + wv[3] * iv[3];
  }
#pragma unroll
  for (int off = 32; off; off >>= 1) sum += __shfl_xor(sum, off, 64);
  if (lane == 0) {
    float a = sum + bias[c];
    out[oidx] = a >= 0.f ? a : 0.01f * a;
  }
}

// ---------------- consolidated prep:
// blocks [0,1024): fused MLP-layer-3 + padded/scaled/c8-blocked bf16 x
//   block = (b, c8, half); each thread: 2 pixel-groups = 16 x-loads in flight.
// blocks [1024,1600): conv_w (O,I,3,3) fp32 -> wt[tap][o][i] bf16.
__global__ void __launch_bounds__(256) prep_all(const float* __restrict__ t1,
                                                const float* __restrict__ w2,
                                                const float* __restrict__ b2,
                                                const float* __restrict__ x,
                                                const float* __restrict__ cw,
                                                unsigned short* __restrict__ xpad,
                                                unsigned short* __restrict__ wt) {
  int blk = blockIdx.x;
  int tid = threadIdx.x;

  if (blk >= 1024) {  // ---- prep_w part
    int idx = (blk - 1024) * 256 + tid;  // 9*256*64 = 147456 threads
    int t = idx / 16384;
    int r = idx - t * 16384;  // o*64 + i4
    int o = r >> 6, i4 = r & 63;
    ushort4v v;
#pragma unroll
    for (int j = 0; j < 4; j++) v[j] = f2bf(cw[(o * 256 + i4 * 4 + j) * 9 + t]);
    *(ushort4v*)(wt + ((size_t)(t * COUT + o)) * CIN + i4 * 4) = v;
    return;
  }

  // ---- prep_x part: blk = (b<<6) | (c8<<1) | h
  int h = blk & 1, c8 = (blk >> 1) & 31, b = blk >> 6;
  int wid = tid >> 6, lane = tid & 63;

  // MLP loads first (longest dependency chain: load -> shuffle tree -> 2 barriers)
  float tv = t1[b * CIN + tid];
  float pj[8];
#pragma unroll
  for (int j = 0; j < 8; j++) pj[j] = w2[(size_t)(c8 * 8 + j) * CIN + tid] * tv;

  // 16 independent x loads (2 pixel-groups x 8 channel-planes)
  const float* xb = x + ((size_t)(b * CIN + c8 * 8)) * (HH * WW);
  int gg0 = h * 512 + tid;  // pixel-group: hh=(gg>>4)+1, w0=(gg&15)*4+1
  int gg1 = gg0 + 256;
  int hh0 = (gg0 >> 4) + 1, w00 = (gg0 & 15) * 4 + 1;
  int hh1 = (gg1 >> 4) + 1, w01 = (gg1 & 15) * 4 + 1;
  int base0 = (hh0 - 1) * WW + (w00 - 1);
  int base1 = (hh1 - 1) * WW + (w01 - 1);
  f32x4 v0[8], v1[8];
#pragma unroll
  for (int j = 0; j < 8; j++) v0[j] = *(const f32x4*)(xb + j * (HH * WW) + base0);
#pragma unroll
  for (int j = 0; j < 8; j++) v1[j] = *(const f32x4*)(xb + j * (HH * WW) + base1);

  // butterfly-reduce the 8 style dots
#pragma unroll
  for (int off = 32; off; off >>= 1)
#pragma unroll
    for (int j = 0; j < 8; j++) pj[j] += __shfl_xor(pj[j], off, 64);
  __shared__ float red[4][8];
  __shared__ float sv_sh[8];
  if (lane == 0)
#pragma unroll
    for (int j = 0; j < 8; j++) red[wid][j] = pj[j];
  __syncthreads();
  if (tid < 8) {
    float a = red[0][tid] + red[1][tid] + red[2][tid] + red[3][tid] + b2[c8 * 8 + tid];
    sv_sh[tid] = a >= 0.f ? a : 0.01f * a;
  }
  __syncthreads();
  float sv[8];
#pragma unroll
  for (int j = 0; j < 8; j++) sv[j] = sv_sh[j];

  unsigned short* xp = xpad + ((size_t)(b * 32 + c8)) * PLANE;

  // zero border: half h covers 130 of the 260 border cells
  if (tid < 130) {
    int i = h * 130 + tid;
    int bh, bw;
    if (i < 66) { bh = 0; bw = i; }
    else if (i < 132) { bh = 65; bw = i - 66; }
    else if (i < 196) { bh = i - 132 + 1; bw = 0; }
    else { bh = i - 196 + 1; bw = 65; }
    ushort8 z = {0, 0, 0, 0, 0, 0, 0, 0};
    *(ushort8*)(xp + (bh * WP + bw) * 8) = z;
  }

  // convert + store (2 groups x 4 px x 8 ch = 2 x 64B contiguous per thread)
  unsigned short* op0 = xp + (hh0 * WP + w00) * 8;
  unsigned short* op1 = xp + (hh1 * WP + w01) * 8;
#pragma unroll
  for (int t2 = 0; t2 < 4; t2++) {
    ushort8 o;
#pragma unroll
    for (int j = 0; j < 8; j++) o[j] = f2bf(v0[j][t2] * sv[j]);
    *(ushort8*)(op0 + t2 * 8) = o;
  }
#pragma unroll
  for (int t2 = 0; t2 < 4; t2++) {
    ushort8 o;
#pragma unroll
    for (int j = 0; j < 8; j++) o[j] = f2bf(v1[j][t2] * sv[j]);
    *(ushort8*)(op1 + t2 * 8) = o;
  }
}

// ---------------- implicit-GEMM conv: BM=128 px, BN=256 out, BK=64 (R4 verbatim)
__device__ __forceinline__ void gl2lds16(const void* g, void* l) {
  __builtin_amdgcn_global_load_lds((const __attribute__((address_space(1))) void*)g,
                                   (__attribute__((address_space(3))) void*)l, 16, 0, 0);
}

__global__ void __launch_bounds__(512, 4) gemm_conv(const unsigned short* __restrict__ xpad,
                                                    const unsigned short* __restrict__ wt,
                                                    float* __restrict__ out) {
  __shared__ unsigned short As[128 * 64];  // [pixel][64ch], 128B rows, XOR-swizzled chunks
  __shared__ unsigned short Bs[256 * 64];  // [o][64ch]
  int tid = threadIdx.x;
  int wid = tid >> 6, lane = tid & 63;
  int bid = blockIdx.x;
  // XCD swizzle: XCD x covers m_t in [x*64, x*64+64) = 2 contiguous images.
  int m_t = (bid & 7) * 64 + (bid >> 3);
  int m0 = m_t << 7;
  int b = m0 >> 12;
  int h0 = (m0 >> 6) & 63;           // tile covers image rows h0, h0+1
  int wm = wid & 1, wn = wid >> 1;   // 2x4 wave grid, each wave 64x64

  f32x4 acc[4][4];
#pragma unroll
  for (int mi = 0; mi < 4; mi++)
#pragma unroll
    for (int ni = 0; ni < 4; ni++) acc[mi][ni] = (f32x4){0.f, 0.f, 0.f, 0.f};

  // ---- stager lane invariants (global lane id = tid)
  int p = tid >> 3;                  // pixel 0..63 (round 1: +64 -> next image row)
  int cs = tid & 7;                  // chunk slot in LDS row
  int gsA = cs ^ (p & 7);            // XOR swizzle: LDS slot cs holds global chunk gsA
  const unsigned short* aL =
      xpad + ((size_t)((b * 32 + gsA) * HP + h0)) * (WP * 8) + p * 8;
  int o_l = tid >> 3;                // o 0..63 within a 64-row round
  const unsigned short* bL = wt + o_l * CIN + (cs ^ (o_l & 7)) * 8;

  char* As_w0 = (char*)As + wid * 1024;
  char* As_w1 = (char*)As + 8192 + wid * 1024;
  char* Bs_w0 = (char*)Bs + wid * 1024;
  char* Bs_w1 = (char*)Bs + 8192 + wid * 1024;
  char* Bs_w2 = (char*)Bs + 16384 + wid * 1024;
  char* Bs_w3 = (char*)Bs + 24576 + wid * 1024;

  // ---- reader frag offsets (bytes into As/Bs), XOR-unswizzled
  int rA = wm * 64 + (lane & 15);
  int rB = wn * 64 + (lane & 15);
  int qa = lane >> 4;
  int offA0 = rA * 128 + ((qa ^ (rA & 7)) * 16);
  int offA1 = rA * 128 + (((qa + 4) ^ (rA & 7)) * 16);
  int offB0 = rB * 128 + ((qa ^ (rB & 7)) * 16);
  int offB1 = rB * 128 + (((qa + 4) ^ (rB & 7)) * 16);

  for (int kh = 0; kh < 3; kh++) {
    for (int kw = 0; kw < 3; kw++) {
      const unsigned short* aT = aL + (kh * WP + kw) * 8;
      const unsigned short* bT = bL + (kh * 3 + kw) * (COUT * CIN);
#pragma unroll
      for (int kc2 = 0; kc2 < 4; kc2++) {
        const unsigned short* aG = aT + kc2 * (8 * PLANE);
        const unsigned short* bG = bT + kc2 * 64;
        gl2lds16(aG, As_w0);
        gl2lds16(aG + WP * 8, As_w1);
        gl2lds16(bG, Bs_w0);
        gl2lds16(bG + 64 * CIN, Bs_w1);
        gl2lds16(bG + 128 * CIN, Bs_w2);
        gl2lds16(bG + 192 * CIN, Bs_w3);
        __syncthreads();
#pragma unroll
        for (int kb = 0; kb < 2; kb++) {
          int oa = kb ? offA1 : offA0;
          int ob = kb ? offB1 : offB0;
          bf16x8 av[4], bv[4];
#pragma unroll
          for (int mi = 0; mi < 4; mi++)
            av[mi] = *(const bf16x8*)((const char*)As + oa + mi * 2048);
#pragma unroll
          for (int ni = 0; ni < 4; ni++)
            bv[ni] = *(const bf16x8*)((const char*)Bs + ob + ni * 2048);
#pragma unroll
          for (int mi = 0; mi < 4; mi++)
#pragma unroll
            for (int ni = 0; ni < 4; ni++)
              acc[mi][ni] = __builtin_amdgcn_mfma_f32_16x16x32_bf16(av[mi], bv[ni],
                                                                    acc[mi][ni], 0, 0, 0);
        }
        __syncthreads();
      }
    }
  }

  // ---- epilogue: D row = pixel (quad*4+reg), col = o (lane&15)
  int pixbase = m0 & 4095;
  int quad = lane >> 4;
  int col = lane & 15;
#pragma unroll
  for (int mi = 0; mi < 4; mi++) {
    int pm = pixbase + wm * 64 + mi * 16 + quad * 4;
#pragma unroll
    for (int ni = 0; ni < 4; ni++) {
      int on = wn * 64 + ni * 16 + col;
      float* op = out + ((size_t)(b * COUT + on) << 12) + pm;
      *(f32x4*)op = acc[mi][ni];
    }
  }
}

extern "C" void kernel_launch(void* const* d_in, const int* in_sizes, int n_in,
                              void* d_out, int out_size, void* d_ws, size_t ws_size,
                              hipStream_t stream) {
  const float* x = (const float*)d_in[0];
  const float* y = (const float*)d_in[1];
  const float* w0 = (const float*)d_in[2];
  const float* b0 = (const float*)d_in[3];
  const float* w1 = (const float*)d_in[4];
  const float* b1 = (const float*)d_in[5];
  const float* w2 = (const float*)d_in[6];
  const float* b2 = (const float*)d_in[7];
  const float* cw = (const float*)d_in[8];
  float* out = (float*)d_out;

  char* ws = (char*)d_ws;
  float* t0 = (float*)ws;                              // 16 KiB
  float* t1 = (float*)(ws + 16384);                    // 16 KiB
  unsigned short* wt = (unsigned short*)(ws + 32768);  // 1.125 MiB
  unsigned short* xpad = (unsigned short*)(ws + 32768 + 9 * COUT * CIN * 2);

  mlp_layer<DCAT><<<BATCH * CIN / 4, 256, 0, stream>>>(y, w0, b0, t0);
  mlp_layer<CIN><<<BATCH * CIN / 4, 256, 0, stream>>>(t0, w1, b1, t1);
  prep_all<<<1024 + 576, 256, 0, stream>>>(t1, w2, b2, x, cw, xpad, wt);
  gemm_conv<<<BATCH * HH * WW / 128, 512, 0, stream>>>(xpad, wt, out);
}